// Round 4
// baseline (531.589 us; speedup 1.0000x reference)
//
#include <hip/hip_runtime.h>
#include <hip/hip_bf16.h>
#include <math.h>

#define S_ 2048
#define D_ 1024
#define H_ 4
#define HD_ 256
#define B_ 4

typedef __hip_bfloat16 bf16;
typedef short s16x8 __attribute__((ext_vector_type(8)));
typedef float f32x4 __attribute__((ext_vector_type(4)));

// async global->LDS, 16B per lane; LDS dest is wave-uniform base + lane*16
#define GLOAD16(g, l)                                             \
    __builtin_amdgcn_global_load_lds(                             \
        (const __attribute__((address_space(1))) void*)(g),       \
        (__attribute__((address_space(3))) void*)(l), 16, 0, 0)

// ---------------------------------------------------------------------------
// MFMA NT GEMM: C[m,n] = sum_k A[m,k]*B[n,k], A/B bf16 row-major.
// 128x128 tile, BK=32, 256 threads = 4 waves (2x2), each wave 4x4 frags of
// 16x16x32 bf16 MFMA.
// MODE: 0 = fp32 store, 1 = bf16 store, 3 = fp32 + legal-bias, written via
// LDS transpose as coalesced float4 (full-line stores avoid write-allocate).
// ---------------------------------------------------------------------------
template <int MODE>
__global__ __launch_bounds__(256) void mfma_nt(
    int K,
    const bf16* __restrict__ A, int lda, long sA_b, long sA_h,
    const bf16* __restrict__ Bm, int ldb, long sB_b, long sB_h,
    void* __restrict__ Cp, int ldc, long sC_b, long sC_h,
    int zdiv, int bbase,
    const double* __restrict__ mag1d, const double* __restrict__ v3d,
    const double* __restrict__ meand, const float* __restrict__ bias_sc)
{
    // union: K-loop uses 2x(128x32) shorts; MODE-3 epilogue reuses as 32x132 fp32
    __shared__ __align__(16) float smem_f[32 * 132];
    short* As = (short*)smem_f;
    short* Bs = As + 128 * 32;

    const int tid = threadIdx.x;
    const int w = tid >> 6, lane = tid & 63;
    const int srow = lane >> 2, scol = (lane & 3) << 3;  // staging: 16 rows/inst
    const int quad = lane >> 4, r = lane & 15;           // mfma fragment coords
    const int wr = (w >> 1) * 64, wc = (w & 1) * 64;     // wave's 64x64 quadrant
    const int zb = blockIdx.z / zdiv, zh = blockIdx.z % zdiv;

    const bf16* Ap = A + (size_t)zb * sA_b + (size_t)zh * sA_h +
                     (size_t)blockIdx.y * 128 * lda;
    const bf16* Bp = Bm + (size_t)zb * sB_b + (size_t)zh * sB_h +
                     (size_t)blockIdx.x * 128 * ldb;

    f32x4 acc[4][4] = {};

    for (int k0 = 0; k0 < K; k0 += 32) {
        if (k0) __syncthreads();  // previous compute done before LDS overwrite
#pragma unroll
        for (int l = 0; l < 2; l++) {
            GLOAD16(Ap + (size_t)(w * 32 + l * 16 + srow) * lda + (k0 + scol),
                    &As[(w * 32 + l * 16) * 32]);
            GLOAD16(Bp + (size_t)(w * 32 + l * 16 + srow) * ldb + (k0 + scol),
                    &Bs[(w * 32 + l * 16) * 32]);
        }
        __syncthreads();  // drains vmcnt (compiler emits waitcnt before barrier)

        s16x8 af[4], bfv[4];
        const s16x8* A8 = (const s16x8*)As;
        const s16x8* B8 = (const s16x8*)Bs;
#pragma unroll
        for (int i = 0; i < 4; i++) af[i] = A8[(wr + i * 16 + r) * 4 + quad];
#pragma unroll
        for (int j = 0; j < 4; j++) bfv[j] = B8[(wc + j * 16 + r) * 4 + quad];
#pragma unroll
        for (int i = 0; i < 4; i++)
#pragma unroll
            for (int j = 0; j < 4; j++)
                acc[i][j] = __builtin_amdgcn_mfma_f32_16x16x32_bf16(
                    af[i], bfv[j], acc[i][j], 0, 0, 0);
    }

    // C/D layout: col = lane&15, row = quad*4 + reg   [m89-verified]
    const int row0 = blockIdx.y * 128 + wr + quad * 4;
    const int col0 = blockIdx.x * 128 + wc + r;

    if (MODE == 0) {
        float* C = (float*)Cp + (size_t)zb * sC_b + (size_t)zh * sC_h;
#pragma unroll
        for (int i = 0; i < 4; i++)
#pragma unroll
            for (int j = 0; j < 4; j++)
#pragma unroll
                for (int p = 0; p < 4; p++)
                    C[(size_t)(row0 + i * 16 + p) * ldc + (col0 + j * 16)] = acc[i][j][p];
    } else if (MODE == 1) {
        bf16* C = (bf16*)Cp + (size_t)zb * sC_b + (size_t)zh * sC_h;
#pragma unroll
        for (int i = 0; i < 4; i++)
#pragma unroll
            for (int j = 0; j < 4; j++)
#pragma unroll
                for (int p = 0; p < 4; p++)
                    C[(size_t)(row0 + i * 16 + p) * ldc + (col0 + j * 16)] =
                        __float2bfloat16(acc[i][j][p]);
    } else {  // MODE 3: scores + legal bias, coalesced via LDS transpose
        float* C = (float*)Cp + (size_t)zb * sC_b + (size_t)zh * sC_h;
        const int h = zh;
        const int bbatch = bbase + zb;
        const float bsc = bias_sc[h];
        const double* src = (h == 1) ? mag1d : v3d;
        const double thr = (h == 1) ? meand[0] : 0.5;
        const int lrbase = (w >> 1) * 16 + quad * 4;  // local row (+p) in chunk
        float* ep = smem_f;                           // 32 x 132 (pad kills 4-way bank conflict)
#pragma unroll
        for (int i = 0; i < 4; i++) {
            __syncthreads();  // LDS free (K-loop / previous chunk reads done)
#pragma unroll
            for (int j = 0; j < 4; j++)
#pragma unroll
                for (int p = 0; p < 4; p++)
                    ep[(lrbase + p) * 132 + wc + j * 16 + r] = acc[i][j][p];
            __syncthreads();
#pragma unroll
            for (int it = 0; it < 4; it++) {
                const int fidx = it * 256 + tid;
                const int lr = fidx >> 5, c4 = (fidx & 31) * 4;
                const int rr = blockIdx.y * 128 + (lr >> 4) * 64 + i * 16 + (lr & 15);
                const int cc0 = blockIdx.x * 128 + c4;
                float4 v = *(float4*)&ep[lr * 132 + c4];
                float bias[4];
                if (h == 0) {
#pragma unroll
                    for (int q = 0; q < 4; q++) bias[q] = (cc0 + q > rr) ? bsc : 0.0f;
                } else if (h == 2) {
#pragma unroll
                    for (int q = 0; q < 4; q++) {
                        int d = cc0 + q - rr; d = d < 0 ? -d : d;
                        bias[q] = bsc * expf(-(float)d * (1.0f / 2048.0f));
                    }
                } else {
                    const double rv = src[(size_t)bbatch * S_ + rr];
#pragma unroll
                    for (int q = 0; q < 4; q++)
                        bias[q] = (rv * src[(size_t)bbatch * S_ + cc0 + q] > thr)
                                      ? bsc : 0.0f;
                }
                v.x += bias[0]; v.y += bias[1]; v.z += bias[2]; v.w += bias[3];
                *(float4*)&C[(size_t)rr * ldc + cc0] = v;
            }
        }
    }
}

// ---------------------------------------------------------------------------
// P.V GEMM, one dispatch for all (b,h): 128x256 tile (N = hd whole -> P read
// exactly once), 512 threads = 8 waves (2 col x 4 row... waves (wy 0..1 rows,
// wx 0..3 cols) each 64x64), BK=32, K = S = 2048 (64 iters).
// P: [B*H, S, S] bf16 compact. Vt: [H, B, hd, S]. concat: [B, S, D].
// ---------------------------------------------------------------------------
__global__ __launch_bounds__(512) void pv_gemm(const bf16* __restrict__ P,
                                               const bf16* __restrict__ Vt,
                                               bf16* __restrict__ concat) {
    __shared__ __align__(16) short As[128 * 32];
    __shared__ __align__(16) short Bs[256 * 32];
    const int tid = threadIdx.x;
    const int w = tid >> 6, lane = tid & 63;
    const int srow = lane >> 2, scol = (lane & 3) << 3;
    const int quad = lane >> 4, r = lane & 15;
    const int wy = w >> 2, wx = w & 3;  // wave tile: rows wy*64, cols wx*64
    const int z = blockIdx.y, b = z >> 2, h = z & 3;
    const bf16* Ap = P + (size_t)z * S_ * S_ + (size_t)blockIdx.x * 128 * S_;
    const bf16* Bp = Vt + ((size_t)h * B_ + b) * HD_ * S_;

    f32x4 acc[4][4] = {};

    for (int k0 = 0; k0 < S_; k0 += 32) {
        if (k0) __syncthreads();
        GLOAD16(Ap + (size_t)(w * 16 + srow) * S_ + (k0 + scol), &As[(w * 16) * 32]);
        GLOAD16(Bp + (size_t)(w * 16 + srow) * S_ + (k0 + scol), &Bs[(w * 16) * 32]);
        GLOAD16(Bp + (size_t)(128 + w * 16 + srow) * S_ + (k0 + scol),
                &Bs[(128 + w * 16) * 32]);
        __syncthreads();

        s16x8 af[4], bfv[4];
        const s16x8* A8 = (const s16x8*)As;
        const s16x8* B8 = (const s16x8*)Bs;
#pragma unroll
        for (int i = 0; i < 4; i++) af[i] = A8[(wy * 64 + i * 16 + r) * 4 + quad];
#pragma unroll
        for (int j = 0; j < 4; j++) bfv[j] = B8[(wx * 64 + j * 16 + r) * 4 + quad];
#pragma unroll
        for (int i = 0; i < 4; i++)
#pragma unroll
            for (int j = 0; j < 4; j++)
                acc[i][j] = __builtin_amdgcn_mfma_f32_16x16x32_bf16(
                    af[i], bfv[j], acc[i][j], 0, 0, 0);
    }

    const int row0 = blockIdx.x * 128 + wy * 64 + quad * 4;
    const int col0 = wx * 64 + r;
    bf16* C = concat + (size_t)b * S_ * D_ + h * HD_;
#pragma unroll
    for (int i = 0; i < 4; i++)
#pragma unroll
        for (int j = 0; j < 4; j++)
#pragma unroll
            for (int p = 0; p < 4; p++)
                C[(size_t)(row0 + i * 16 + p) * D_ + (col0 + j * 16)] =
                    __float2bfloat16(acc[i][j][p]);
}

// fp32 -> bf16 (optionally scaled), 4 elems/thread
__global__ __launch_bounds__(256) void cvt_bf16(const float* __restrict__ in,
                                                bf16* __restrict__ out, int n,
                                                float scale) {
    const size_t i0 = ((size_t)blockIdx.x * 256 + threadIdx.x) * 4;
    if (i0 + 3 < (size_t)n) {
        const float4 v = *(const float4*)(in + i0);
        out[i0 + 0] = __float2bfloat16(v.x * scale);
        out[i0 + 1] = __float2bfloat16(v.y * scale);
        out[i0 + 2] = __float2bfloat16(v.z * scale);
        out[i0 + 3] = __float2bfloat16(v.w * scale);
    }
}

// Vraw [H, B*S, hd] -> Vt [H, B, hd, S]  (64x64 bf16 LDS tile transpose)
__global__ __launch_bounds__(256) void transpose_v(const bf16* __restrict__ in,
                                                   bf16* __restrict__ out) {
    const int h = blockIdx.z / B_, b = blockIdx.z % B_;
    const int e0 = blockIdx.x * 64, s0 = blockIdx.y * 64;
    __shared__ short t[64][66];
    const int tid = threadIdx.x;
    const int rr = tid >> 2;
    const int cc = (tid & 3) << 4;
    const bf16* ip = in + (((size_t)h * B_ * S_) + (size_t)b * S_ + s0) * HD_ + e0;
    const s16x8 v0 = *(const s16x8*)(ip + (size_t)rr * HD_ + cc);
    const s16x8 v1 = *(const s16x8*)(ip + (size_t)rr * HD_ + cc + 8);
#pragma unroll
    for (int i = 0; i < 8; i++) {
        t[rr][cc + i] = v0[i];
        t[rr][cc + 8 + i] = v1[i];
    }
    __syncthreads();
    bf16* op = out + (((size_t)h * B_ + b) * HD_ + e0 + rr) * S_ + s0 + cc;
    s16x8 o0, o1;
#pragma unroll
    for (int i = 0; i < 8; i++) {
        o0[i] = t[cc + i][rr];
        o1[i] = t[cc + 8 + i][rr];
    }
    *(s16x8*)op = o0;
    *(s16x8*)(op + 8) = o1;
}

// mag1[b,s] = ||emb[b,s,256:512]|| (fp64), v3[b,s] = emb[b,s,1023]
__global__ __launch_bounds__(256) void prep_kernel(const float* __restrict__ emb,
                                                   double* __restrict__ mag1d,
                                                   double* __restrict__ v3d) {
    const long row = blockIdx.x;
    const int tid = threadIdx.x;
    const float x = emb[row * D_ + 256 + tid];
    __shared__ double red[256];
    red[tid] = (double)x * (double)x;
    __syncthreads();
    for (int off = 128; off > 0; off >>= 1) {
        if (tid < off) red[tid] += red[tid + off];
        __syncthreads();
    }
    if (tid == 0) {
        mag1d[row] = sqrt(red[0]);
        v3d[row] = (double)emb[row * D_ + 1023];
    }
}

__global__ __launch_bounds__(256) void mean_kernel(const double* __restrict__ mag1d,
                                                   double* __restrict__ meand) {
    const int tid = threadIdx.x;
    __shared__ double red[256];
    double acc = 0.0;
    for (int b = 0; b < B_; b++) {
        double ss = 0.0;
        for (int i = tid; i < S_; i += 256) ss += mag1d[(long)b * S_ + i];
        __syncthreads();
        red[tid] = ss;
        __syncthreads();
        for (int off = 128; off > 0; off >>= 1) {
            if (tid < off) red[tid] += red[tid + off];
            __syncthreads();
        }
        if (tid == 0) {
            const double rb = red[0] / (double)S_;
            acc += rb * rb;
        }
        __syncthreads();
    }
    if (tid == 0) meand[0] = acc / (double)B_;
}

// Softmax for rows {2i, 2i+1} of all 4 heads (one b). Writes P bf16 at
// (p_h, p_row) strides (compact buffer OR in-place-over-scores fallback;
// both rows are fully read before any P write), accumulates avgw + rowsum.
// Same per-row op order as R2/R3.
__global__ __launch_bounds__(256) void softmax2(
    const float* __restrict__ scores, bf16* __restrict__ P, long p_h, long p_row,
    float* __restrict__ avgw, float* __restrict__ rowsum) {
    const int s0 = blockIdx.x * 2, tid = threadIdx.x;
    __shared__ float2 red[256];
    float wa0[8] = {0, 0, 0, 0, 0, 0, 0, 0};
    float wa1[8] = {0, 0, 0, 0, 0, 0, 0, 0};
    for (int h = 0; h < H_; h++) {
        const float* r0 = scores + ((size_t)h * S_ + s0) * S_;
        const float* r1 = r0 + S_;
        float v0[8], v1[8];
        float m0 = -1e30f, m1 = -1e30f;
#pragma unroll
        for (int i = 0; i < 8; i++) {
            v0[i] = r0[tid + 256 * i];
            m0 = fmaxf(m0, v0[i]);
            v1[i] = r1[tid + 256 * i];
            m1 = fmaxf(m1, v1[i]);
        }
        red[tid] = make_float2(m0, m1);
        __syncthreads();
        for (int off = 128; off > 0; off >>= 1) {
            if (tid < off) {
                red[tid].x = fmaxf(red[tid].x, red[tid + off].x);
                red[tid].y = fmaxf(red[tid].y, red[tid + off].y);
            }
            __syncthreads();
        }
        m0 = red[0].x;
        m1 = red[0].y;
        __syncthreads();
        float s0s = 0.0f, s1s = 0.0f;
#pragma unroll
        for (int i = 0; i < 8; i++) {
            v0[i] = expf(v0[i] - m0);
            s0s += v0[i];
            v1[i] = expf(v1[i] - m1);
            s1s += v1[i];
        }
        red[tid] = make_float2(s0s, s1s);
        __syncthreads();
        for (int off = 128; off > 0; off >>= 1) {
            if (tid < off) {
                red[tid].x += red[tid + off].x;
                red[tid].y += red[tid + off].y;
            }
            __syncthreads();
        }
        const float inv0 = 1.0f / red[0].x;
        const float inv1 = 1.0f / red[0].y;
        __syncthreads();
        bf16* p0 = P + (size_t)h * p_h + (size_t)s0 * p_row;
        bf16* p1 = p0 + p_row;
#pragma unroll
        for (int i = 0; i < 8; i++) {
            const float w0 = v0[i] * inv0;
            p0[tid + 256 * i] = __float2bfloat16(w0);
            wa0[i] += w0;
            const float w1 = v1[i] * inv1;
            p1[tid + 256 * i] = __float2bfloat16(w1);
            wa1[i] += w1;
        }
    }
    float as0 = 0.0f, as1 = 0.0f;
#pragma unroll
    for (int i = 0; i < 8; i++) {
        const float a0 = wa0[i] * 0.25f;
        avgw[(size_t)s0 * S_ + tid + 256 * i] = a0;
        as0 += a0;
        const float a1 = wa1[i] * 0.25f;
        avgw[(size_t)(s0 + 1) * S_ + tid + 256 * i] = a1;
        as1 += a1;
    }
    red[tid] = make_float2(as0, as1);
    __syncthreads();
    for (int off = 128; off > 0; off >>= 1) {
        if (tid < off) {
            red[tid].x += red[tid + off].x;
            red[tid].y += red[tid + off].y;
        }
        __syncthreads();
    }
    if (tid == 0) {
        rowsum[s0] = red[0].x;
        rowsum[s0 + 1] = red[0].y;
    }
}

// y = proj + Wo_b + emb; LayerNorm(y) in place
__global__ __launch_bounds__(256) void ln_kernel(float* __restrict__ out,
                                                 const float* __restrict__ emb,
                                                 const float* __restrict__ wob,
                                                 const float* __restrict__ g,
                                                 const float* __restrict__ beta) {
    const long row = blockIdx.x;
    float* o = out + row * D_;
    const float* e = emb + row * D_;
    const int tid = threadIdx.x;
    __shared__ float red[256];
    float v[4];
    float sum = 0.0f;
#pragma unroll
    for (int i = 0; i < 4; i++) {
        const int c = tid + 256 * i;
        v[i] = o[c] + wob[c] + e[c];
        sum += v[i];
    }
    red[tid] = sum;
    __syncthreads();
    for (int off = 128; off > 0; off >>= 1) {
        if (tid < off) red[tid] += red[tid + off];
        __syncthreads();
    }
    const float mu = red[0] * (1.0f / 1024.0f);
    __syncthreads();
    float vs = 0.0f;
#pragma unroll
    for (int i = 0; i < 4; i++) {
        const float d = v[i] - mu;
        vs += d * d;
    }
    red[tid] = vs;
    __syncthreads();
    for (int off = 128; off > 0; off >>= 1) {
        if (tid < off) red[tid] += red[tid + off];
        __syncthreads();
    }
    const float var = red[0] * (1.0f / 1024.0f);
    const float inv = 1.0f / sqrtf(var + 1e-5f);
#pragma unroll
    for (int i = 0; i < 4; i++) {
        const int c = tid + 256 * i;
        o[c] = (v[i] - mu) * inv * g[c] + beta[c];
    }
}

__global__ __launch_bounds__(256) void guilt_kernel(const float* __restrict__ rowsum,
                                                    float* __restrict__ guilt) {
    const int b = blockIdx.x, tid = threadIdx.x;
    const float* r = rowsum + (long)b * S_;
    float* gq = guilt + (long)b * S_;
    __shared__ float red[256];
    float v[8];
    float m = -1e30f;
#pragma unroll
    for (int i = 0; i < 8; i++) {
        v[i] = r[tid + 256 * i];
        m = fmaxf(m, v[i]);
    }
    red[tid] = m;
    __syncthreads();
    for (int off = 128; off > 0; off >>= 1) {
        if (tid < off) red[tid] = fmaxf(red[tid], red[tid + off]);
        __syncthreads();
    }
    m = red[0];
    __syncthreads();
    float sum = 0.0f;
#pragma unroll
    for (int i = 0; i < 8; i++) {
        v[i] = expf(v[i] - m);
        sum += v[i];
    }
    red[tid] = sum;
    __syncthreads();
    for (int off = 128; off > 0; off >>= 1) {
        if (tid < off) red[tid] += red[tid + off];
        __syncthreads();
    }
    const float inv = 1.0f / red[0];
#pragma unroll
    for (int i = 0; i < 8; i++) gq[tid + 256 * i] = v[i] * inv;
}

extern "C" void kernel_launch(void* const* d_in, const int* in_sizes, int n_in,
                              void* d_out, int out_size, void* d_ws, size_t ws_size,
                              hipStream_t stream) {
    const float* emb = (const float*)d_in[0];
    const float* Wq = (const float*)d_in[1];
    const float* Wk = (const float*)d_in[2];
    const float* Wv = (const float*)d_in[3];
    const float* bias_sc = (const float*)d_in[4];
    const float* Wo_w = (const float*)d_in[5];
    const float* Wo_b = (const float*)d_in[6];
    const float* ln_g = (const float*)d_in[7];
    const float* ln_bt = (const float*)d_in[8];

    char* ws = (char*)d_ws;
    size_t off = 0;
    auto alloc = [&](size_t bytes) {
        size_t o = off;
        off = (off + bytes + 255) & ~(size_t)255;
        return o;
    };
    bf16* embb = (bf16*)(ws + alloc((size_t)B_ * S_ * D_ * 2));
    bf16* concat = embb;  // alias: embb dead after QKV GEMMs, concat written later
    bf16* Qm = (bf16*)(ws + alloc((size_t)H_ * B_ * S_ * HD_ * 2));  // [H,B*S,hd]
    bf16* Km = (bf16*)(ws + alloc((size_t)H_ * B_ * S_ * HD_ * 2));
    bf16* Vtb = (bf16*)(ws + alloc((size_t)H_ * B_ * HD_ * S_ * 2)); // [H,B,hd,S]
    bf16* Wqb = (bf16*)(ws + alloc((size_t)H_ * HD_ * HD_ * 2));
    bf16* Wkb = (bf16*)(ws + alloc((size_t)H_ * HD_ * HD_ * 2));
    bf16* Wvb = (bf16*)(ws + alloc((size_t)H_ * HD_ * HD_ * 2));
    bf16* Wob = (bf16*)(ws + alloc((size_t)D_ * D_ * 2));
    double* mag1d = (double*)(ws + alloc((size_t)B_ * S_ * 8));
    double* v3d = (double*)(ws + alloc((size_t)B_ * S_ * 8));
    double* meand = (double*)(ws + alloc(256));
    float* rowsum = (float*)(ws + alloc((size_t)B_ * S_ * 4));
    float* scores = (float*)(ws + alloc((size_t)H_ * S_ * S_ * 4));  // one b
    bf16* Vraw = (bf16*)scores;  // alias: consumed by transpose before scores b=0
    bf16* P = (bf16*)(ws + off);  // batched path: [B,H,S,S] bf16 compact
    const size_t need_batched = off + (size_t)B_ * H_ * S_ * S_ * 2;
    const bool batched = ws_size >= need_batched;  // proven true in R3

    float* outp = (float*)d_out;
    float* avgw = outp + (size_t)B_ * S_ * D_;
    float* guilt = avgw + (size_t)B_ * S_ * S_;

    // casts (Q-scale 1/16 folded into Wq)
    cvt_bf16<<<(B_ * S_ * D_) / 1024, 256, 0, stream>>>(emb, embb, B_ * S_ * D_, 1.0f);
    cvt_bf16<<<(H_ * HD_ * HD_) / 1024, 256, 0, stream>>>(Wq, Wqb, H_ * HD_ * HD_, 0.0625f);
    cvt_bf16<<<(H_ * HD_ * HD_) / 1024, 256, 0, stream>>>(Wk, Wkb, H_ * HD_ * HD_, 1.0f);
    cvt_bf16<<<(H_ * HD_ * HD_) / 1024, 256, 0, stream>>>(Wv, Wvb, H_ * HD_ * HD_, 1.0f);
    cvt_bf16<<<(D_ * D_) / 1024, 256, 0, stream>>>(Wo_w, Wob, D_ * D_, 1.0f);

    prep_kernel<<<B_ * S_, 256, 0, stream>>>(emb, mag1d, v3d);
    mean_kernel<<<1, 256, 0, stream>>>(mag1d, meand);

    // QKV projections: MFMA, M = B*S, N = hd, K = hd, z = head
    {
        const dim3 g(HD_ / 128, (B_ * S_) / 128, H_);
        const long sQ = (long)B_ * S_ * HD_;
        mfma_nt<1><<<g, 256, 0, stream>>>(HD_, embb, D_, 0, HD_,
                                          Wqb, HD_, 0, (long)HD_ * HD_,
                                          Qm, HD_, 0, sQ, H_, 0,
                                          nullptr, nullptr, nullptr, nullptr);
        mfma_nt<1><<<g, 256, 0, stream>>>(HD_, embb, D_, 0, HD_,
                                          Wkb, HD_, 0, (long)HD_ * HD_,
                                          Km, HD_, 0, sQ, H_, 0,
                                          nullptr, nullptr, nullptr, nullptr);
        mfma_nt<1><<<g, 256, 0, stream>>>(HD_, embb, D_, 0, HD_,
                                          Wvb, HD_, 0, (long)HD_ * HD_,
                                          Vraw, HD_, 0, sQ, H_, 0,
                                          nullptr, nullptr, nullptr, nullptr);
    }
    transpose_v<<<dim3(HD_ / 64, S_ / 64, H_ * B_), 256, 0, stream>>>(Vraw, Vtb);

    for (int b = 0; b < B_; b++) {
        // scores[h,s,t] = Q.K^T + bias  (fp32 out, coalesced full-line stores)
        mfma_nt<3><<<dim3(S_ / 128, S_ / 128, H_), 256, 0, stream>>>(
            HD_,
            Qm + (size_t)b * S_ * HD_, HD_, 0, (long)B_ * S_ * HD_,
            Km + (size_t)b * S_ * HD_, HD_, 0, (long)B_ * S_ * HD_,
            scores, S_, 0, (long)S_ * S_,
            H_, b, mag1d, v3d, meand, bias_sc);
        if (batched) {
            softmax2<<<S_ / 2, 256, 0, stream>>>(
                scores, P + (size_t)b * H_ * S_ * S_, (long)S_ * S_, S_,
                avgw + (size_t)b * S_ * S_, rowsum + (size_t)b * S_);
        } else {
            // P bf16 in place over the fp32 scores rows (row stride 2S)
            softmax2<<<S_ / 2, 256, 0, stream>>>(
                scores, (bf16*)scores, 2L * S_ * S_, 2 * S_,
                avgw + (size_t)b * S_ * S_, rowsum + (size_t)b * S_);
            mfma_nt<1><<<dim3(HD_ / 128, S_ / 128, H_), 256, 0, stream>>>(
                S_,
                (const bf16*)scores, 2 * S_, 0, 2L * S_ * S_,
                Vtb + (size_t)b * HD_ * S_, S_, 0, (long)B_ * HD_ * S_,
                concat + (size_t)b * S_ * D_, D_, 0, HD_,
                H_, 0, nullptr, nullptr, nullptr, nullptr);
        }
    }
    if (batched) {
        // attended = P.V for all (b,h): P read exactly once (N = hd in-block)
        pv_gemm<<<dim3(S_ / 128, B_ * H_), 512, 0, stream>>>(P, Vtb, concat);
    }

    // out = concat @ Wo^T (MFMA, bf16 Wo)
    mfma_nt<0><<<dim3(D_ / 128, (B_ * S_) / 128, 1), 256, 0, stream>>>(
        D_, concat, D_, 0, 0, Wob, D_, 0, 0, outp, D_, 0, 0,
        1, 0, nullptr, nullptr, nullptr, nullptr);

    ln_kernel<<<B_ * S_, 256, 0, stream>>>(outp, emb, Wo_b, ln_g, ln_bt);
    guilt_kernel<<<B_, 256, 0, stream>>>(rowsum, guilt);
}